// Round 5
// baseline (4748.133 us; speedup 1.0000x reference)
//
#include <hip/hip_runtime.h>

#define TINN 512
#define FF 64
#define HHD 512
#define TOUTN 64

using v8h = __attribute__((ext_vector_type(8))) _Float16;
using v4h = __attribute__((ext_vector_type(4))) _Float16;
using v4f = __attribute__((ext_vector_type(4))) float;
using u32x4 = __attribute__((ext_vector_type(4))) unsigned int;
using u64 = unsigned long long;

#define AGT __HIP_MEMORY_SCOPE_AGENT

// ---------------- LDS layout (bytes) ----------------
#define WOFF 0            // weights, MFMA fragment order (max 128KB)
#define BIAS_OFF 131072
#define WIH0_OFF 131328
#define PREV_OFF 131584
#define PART_OFF 131840
#define PROJW_OFF 132864
#define PROJB_OFF 134912
#define TRANS_OFF 134976  // 4 waves x 512B h-transpose scratch
#define SMEM_TOTAL 137024

// ---------------- workspace layout ----------------
// REPLICATED progress flags, then h0/h1 ring buffers.
// DEEP mode (ws >= 9MB, certain): 16-deep rings + CACHED consumer loads +
// agent-acquire fence every 10 steps. Producer stores stay cache-bypass
// (LLC fresh before the flag). A cached line is re-read only one ring lap
// (16 steps) later, and >=1 fence falls in any 16-step window, so stale
// lines are always invalidated between uses. (R2 validated the
// fence+cached protocol correctness per-step; here it is amortized 10x.)
// XCD-PAIR PLACEMENT: bid%8 is the XCD on MI355X. group g's 64 blocks map
// to XCDs {2g,2g+1}, so a group's h lines live in exactly 2 L2s: consumer
// loads become L2 hits and LLC-level h traffic drops 32x vs bypass.
#define WS_BAR 0
#define WS_FLAG_BYTES (4 * 64 * 64 * 64)   // 1 MiB
#define WS_HOFF WS_FLAG_BYTES
#define HBYTES (256 * HHD * 2)             // 256 KiB per ring slot
#define WS_NEED_DEEP (WS_FLAG_BYTES + (size_t)32 * HBYTES)   // 9 MB
#define INV_PERIOD 10

static __device__ __forceinline__ float sigm(float x) { return 1.0f / (1.0f + __expf(-x)); }
static __device__ __forceinline__ float tanh_f(float x) { return 1.0f - 2.0f / (1.0f + __expf(2.0f * x)); }

static __device__ __forceinline__ v8h aload16(const _Float16* p) {
  union { u64 u[2]; v8h h; } c;
  const u64* q = (const u64*)p;
  c.u[0] = __hip_atomic_load(q, __ATOMIC_RELAXED, AGT);
  c.u[1] = __hip_atomic_load(q + 1, __ATOMIC_RELAXED, AGT);
  return c.h;
}
static __device__ __forceinline__ void astore8(_Float16* p, v4h v) {
  union { u64 u; v4h h; } c;
  c.h = v;
  __hip_atomic_store((u64*)p, c.u, __ATOMIC_RELAXED, AGT);
}
static __device__ __forceinline__ void astore8z(void* p) {
  __hip_atomic_store((u64*)p, 0ull, __ATOMIC_RELAXED, AGT);
}
static __device__ __forceinline__ void acquireFence() {
  __builtin_amdgcn_fence(__ATOMIC_ACQUIRE, "agent");   // waitcnt + buffer_inv
}

#if __has_builtin(__builtin_amdgcn_raw_ptr_buffer_load_b128) && \
    __has_builtin(__builtin_amdgcn_make_buffer_rsrc)
#define HAVE_BUFLOAD 1
using rsrc_t = __amdgpu_buffer_rsrc_t;
static __device__ __forceinline__ rsrc_t mkrsrc(const void* p) {
  return __builtin_amdgcn_make_buffer_rsrc((void*)p, (short)0, 0xFFFFFFFFu, 0x00020000);
}
static __device__ __forceinline__ v8h bload16(rsrc_t r, int byteOff) {
  union { u32x4 u; v8h h; } c;
  c.u = __builtin_amdgcn_raw_ptr_buffer_load_b128(r, byteOff, 0, 17);  // sc0|sc1
  return c.h;
}
#endif

// Producer broadcast: after all h stores are acked (waitcnt 0 + barrier),
// lanes 0..63 each store `val` into one consumer's private slot.
static __device__ __forceinline__ void signalDone(unsigned* flagsG, int mySlot, unsigned val) {
  __builtin_amdgcn_s_waitcnt(0);
  __syncthreads();
  if (threadIdx.x < 64) {
    unsigned* p = flagsG + ((size_t)threadIdx.x * 64 + mySlot) * 16;
    __hip_atomic_store(p, val, __ATOMIC_RELAXED, AGT);
  }
}

// Poll base..base+31 of THIS consumer's private slots until all >= tgt.
static __device__ __forceinline__ void waitRolePriv(unsigned* myflags, int base, int tgt) {
  if (tgt > 0) {
    if (threadIdx.x < 32) {
      unsigned* p = myflags + (size_t)(base + threadIdx.x) * 16;
      while ((int)__hip_atomic_load(p, __ATOMIC_RELAXED, AGT) < tgt)
        __builtin_amdgcn_s_sleep(1);
    }
    __syncthreads();
#if __has_builtin(__builtin_amdgcn_sched_barrier)
    __builtin_amdgcn_sched_barrier(0);
#endif
  }
}

// Dual-role poll on private slots: lanes 0-31 poll role0 (tgt0), lanes
// 32-63 poll role1 (tgt1). tgt <= 0 skips that role.
static __device__ __forceinline__ void waitRolesPriv(unsigned* myflags, int tgt0, int tgt1) {
  int t = threadIdx.x;
  if (t < 64) {
    int tgt = (t < 32) ? tgt0 : tgt1;
    if (tgt > 0) {
      unsigned* p = myflags + (size_t)t * 16;
      while ((int)__hip_atomic_load(p, __ATOMIC_RELAXED, AGT) < tgt)
        __builtin_amdgcn_s_sleep(1);
    }
  }
  __syncthreads();
#if __has_builtin(__builtin_amdgcn_sched_barrier)
  __builtin_amdgcn_sched_barrier(0);
#endif
}

// Weight slice (64 gate-cols x K) fp32->fp16 into LDS, fragment order.
static __device__ __attribute__((noinline)) void loadWeights(
    int tid, int hc0, const float* W1, int ld1, int K1,
    const float* W2, int K) {
  extern __shared__ char smem[];
  int c = tid >> 2, sub = tid & 3;
  int nt = c >> 4, l = c & 15;
  int n = nt * HHD + hc0 + l;
  int Kq = K >> 2;
  for (int k = sub * Kq; k < (sub + 1) * Kq; ++k) {
    float v;
    if (k < K1) v = W1[(size_t)n * ld1 + k];
    else        v = W2[(size_t)n * HHD + (k - K1)];
    int kc = k >> 6, ks = (k >> 5) & 1, quad = (k >> 3) & 3, j = k & 7;
    int off = (((kc * 2 + ks) * 4 + nt) * 64 + quad * 16 + l) * 16 + j * 2;
    *(_Float16*)(smem + WOFF + off) = (_Float16)v;
  }
}

// 8 K-chunks of MFMA from swizzled src, weight chunks WC0..WC0+7.
// DEEP: plain cached loads (L2 allocate; freshness by ring+periodic inv).
// Shallow: LLC-bypass loads.
template <int WC0, bool DEEP>
static __device__ __forceinline__ void mfma8(
    const _Float16* src, int rt, int lane, const char* wbLane, v4f* acc) {
#if HAVE_BUFLOAD
  rsrc_t rs;
  if constexpr (!DEEP) rs = mkrsrc(src);
#endif
#pragma unroll
  for (int kc = 0; kc < 8; ++kc) {
    int off = rt * 16384 + kc * 2048 + lane * 16;
    v8h ak0, ak1;
    if constexpr (DEEP) {
      ak0 = *(const v8h*)((const char*)src + off);
      ak1 = *(const v8h*)((const char*)src + off + 1024);
    } else {
#if HAVE_BUFLOAD
      ak0 = bload16(rs, off);
      ak1 = bload16(rs, off + 1024);
#else
      ak0 = aload16(src + off / 2);
      ak1 = aload16(src + (off + 1024) / 2);
#endif
    }
    const char* bb = wbLane + (size_t)(WC0 + kc) * 8192;
#pragma unroll
    for (int ks = 0; ks < 2; ++ks) {
      v8h a = ks ? ak1 : ak0;
      acc[0] = __builtin_amdgcn_mfma_f32_16x16x32_f16(a, *(const v8h*)(bb + (ks * 4 + 0) * 1024), acc[0], 0, 0, 0);
      acc[1] = __builtin_amdgcn_mfma_f32_16x16x32_f16(a, *(const v8h*)(bb + (ks * 4 + 1) * 1024), acc[1], 0, 0, 0);
      acc[2] = __builtin_amdgcn_mfma_f32_16x16x32_f16(a, *(const v8h*)(bb + (ks * 4 + 2) * 1024), acc[2], 0, 0, 0);
      acc[3] = __builtin_amdgcn_mfma_f32_16x16x32_f16(a, *(const v8h*)(bb + (ks * 4 + 3) * 1024), acc[3], 0, 0, 0);
    }
  }
}

// Fused double-source MFMA for stepL1: all 32 A-loads (h1 then h0) issued
// before any MFMA. h1 -> weight chunks 8..15, h0 -> weight chunks 0..7.
template <bool DEEP>
static __device__ __forceinline__ void mfmaDual(
    const _Float16* h0src, const _Float16* h1src, int rt, int lane,
    const char* wbLane, v4f* acc) {
  v8h a1[16], a0[16];
  if constexpr (DEEP) {
#pragma unroll
    for (int kc = 0; kc < 8; ++kc) {
      int off = rt * 16384 + kc * 2048 + lane * 16;
      a1[2 * kc]     = *(const v8h*)((const char*)h1src + off);
      a1[2 * kc + 1] = *(const v8h*)((const char*)h1src + off + 1024);
    }
#pragma unroll
    for (int kc = 0; kc < 8; ++kc) {
      int off = rt * 16384 + kc * 2048 + lane * 16;
      a0[2 * kc]     = *(const v8h*)((const char*)h0src + off);
      a0[2 * kc + 1] = *(const v8h*)((const char*)h0src + off + 1024);
    }
  } else {
#if HAVE_BUFLOAD
    rsrc_t r1 = mkrsrc(h1src);
    rsrc_t r0 = mkrsrc(h0src);
#pragma unroll
    for (int kc = 0; kc < 8; ++kc) {
      int off = rt * 16384 + kc * 2048 + lane * 16;
      a1[2 * kc]     = bload16(r1, off);
      a1[2 * kc + 1] = bload16(r1, off + 1024);
    }
#pragma unroll
    for (int kc = 0; kc < 8; ++kc) {
      int off = rt * 16384 + kc * 2048 + lane * 16;
      a0[2 * kc]     = bload16(r0, off);
      a0[2 * kc + 1] = bload16(r0, off + 1024);
    }
#else
#pragma unroll
    for (int kc = 0; kc < 8; ++kc) {
      int off = rt * 16384 + kc * 2048 + lane * 16;
      a1[2 * kc]     = aload16(h1src + off / 2);
      a1[2 * kc + 1] = aload16(h1src + (off + 1024) / 2);
    }
#pragma unroll
    for (int kc = 0; kc < 8; ++kc) {
      int off = rt * 16384 + kc * 2048 + lane * 16;
      a0[2 * kc]     = aload16(h0src + off / 2);
      a0[2 * kc + 1] = aload16(h0src + (off + 1024) / 2);
    }
#endif
  }
#pragma unroll
  for (int kc = 0; kc < 8; ++kc) {
    const char* bb = wbLane + (size_t)(8 + kc) * 8192;
#pragma unroll
    for (int ks = 0; ks < 2; ++ks) {
      v8h a = a1[2 * kc + ks];
      acc[0] = __builtin_amdgcn_mfma_f32_16x16x32_f16(a, *(const v8h*)(bb + (ks * 4 + 0) * 1024), acc[0], 0, 0, 0);
      acc[1] = __builtin_amdgcn_mfma_f32_16x16x32_f16(a, *(const v8h*)(bb + (ks * 4 + 1) * 1024), acc[1], 0, 0, 0);
      acc[2] = __builtin_amdgcn_mfma_f32_16x16x32_f16(a, *(const v8h*)(bb + (ks * 4 + 2) * 1024), acc[2], 0, 0, 0);
      acc[3] = __builtin_amdgcn_mfma_f32_16x16x32_f16(a, *(const v8h*)(bb + (ks * 4 + 3) * 1024), acc[3], 0, 0, 0);
    }
  }
#pragma unroll
  for (int kc = 0; kc < 8; ++kc) {
    const char* bb = wbLane + (size_t)kc * 8192;
#pragma unroll
    for (int ks = 0; ks < 2; ++ks) {
      v8h a = a0[2 * kc + ks];
      acc[0] = __builtin_amdgcn_mfma_f32_16x16x32_f16(a, *(const v8h*)(bb + (ks * 4 + 0) * 1024), acc[0], 0, 0, 0);
      acc[1] = __builtin_amdgcn_mfma_f32_16x16x32_f16(a, *(const v8h*)(bb + (ks * 4 + 1) * 1024), acc[1], 0, 0, 0);
      acc[2] = __builtin_amdgcn_mfma_f32_16x16x32_f16(a, *(const v8h*)(bb + (ks * 4 + 2) * 1024), acc[2], 0, 0, 0);
      acc[3] = __builtin_amdgcn_mfma_f32_16x16x32_f16(a, *(const v8h*)(bb + (ks * 4 + 3) * 1024), acc[3], 0, 0, 0);
    }
  }
}

// x chunk (weight chunk 0): raw fp32 x, cached (read-only -> inv-safe).
static __device__ __forceinline__ void xChunk(
    const float* xstep, int m0, int tid, const char* wbLane, v4f* acc) {
  int lane = tid & 63, wave = tid >> 6;
  int l15 = lane & 15, quad = lane >> 4;
  v8h ak0, ak1;
  int ra = m0 + wave * 16 + l15;
  const float* xr = xstep + (size_t)ra * (TINN * FF) + quad * 8;
  v4f f00 = *(const v4f*)(xr);
  v4f f01 = *(const v4f*)(xr + 4);
  v4f f10 = *(const v4f*)(xr + 32);
  v4f f11 = *(const v4f*)(xr + 36);
#pragma unroll
  for (int e = 0; e < 4; ++e) {
    ak0[e] = (_Float16)f00[e]; ak0[4 + e] = (_Float16)f01[e];
    ak1[e] = (_Float16)f10[e]; ak1[4 + e] = (_Float16)f11[e];
  }
#pragma unroll
  for (int ks = 0; ks < 2; ++ks) {
    v8h a = ks ? ak1 : ak0;
    acc[0] = __builtin_amdgcn_mfma_f32_16x16x32_f16(a, *(const v8h*)(wbLane + (ks * 4 + 0) * 1024), acc[0], 0, 0, 0);
    acc[1] = __builtin_amdgcn_mfma_f32_16x16x32_f16(a, *(const v8h*)(wbLane + (ks * 4 + 1) * 1024), acc[1], 0, 0, 0);
    acc[2] = __builtin_amdgcn_mfma_f32_16x16x32_f16(a, *(const v8h*)(wbLane + (ks * 4 + 2) * 1024), acc[2], 0, 0, 0);
    acc[3] = __builtin_amdgcn_mfma_f32_16x16x32_f16(a, *(const v8h*)(wbLane + (ks * 4 + 3) * 1024), acc[3], 0, 0, 0);
  }
}

// In-register gate math + per-wave LDS mini-transpose for a coalesced 8B
// h write (bypass store: fresh at LLC before the flag).
static __device__ __forceinline__ void epilogue(
    int tid, int m0, int hc0, int rank1, _Float16* hout, float* creg, v4f* acc) {
  extern __shared__ char smem[];
  int lane = tid & 63, wave = tid >> 6;
  int l15 = lane & 15, quad = lane >> 4;
  float* bias = (float*)(smem + BIAS_OFF);
  float bi = bias[l15], bf = bias[16 + l15], bg = bias[32 + l15], bo = bias[48 + l15];
  float wi = 0.f, wf = 0.f, wg = 0.f, wo = 0.f;
  if (rank1) {
    float* wih0 = (float*)(smem + WIH0_OFF);
    wi = wih0[l15]; wf = wih0[16 + l15]; wg = wih0[32 + l15]; wo = wih0[48 + l15];
  }
  float* prevl = (float*)(smem + PREV_OFF);
  _Float16* tb = (_Float16*)(smem + TRANS_OFF + (size_t)wave * 512);
#pragma unroll
  for (int r = 0; r < 4; ++r) {
    int mloc = wave * 16 + quad * 4 + r;
    float gi = acc[0][r] + bi, gf = acc[1][r] + bf;
    float gg = acc[2][r] + bg, go = acc[3][r] + bo;
    if (rank1) {
      float pv = prevl[mloc];
      gi += pv * wi; gf += pv * wf; gg += pv * wg; go += pv * wo;
    }
    float cc = sigm(gf) * creg[r] + sigm(gi) * tanh_f(gg);
    float h = sigm(go) * tanh_f(cc);
    creg[r] = cc;
    tb[(quad * 4 + r) * 16 + l15] = (_Float16)h;   // m-fast deposit
  }
  {
    int mloc = lane & 15, cg = lane >> 4;
    v4h hv = *(const v4h*)(tb + mloc * 16 + cg * 4);
    int m = m0 + wave * 16 + mloc;
    int c0 = hc0 + cg * 4;
    int off = (m >> 4) * 16384 + (c0 >> 6) * 2048 + ((c0 >> 5) & 1) * 1024 +
              ((c0 >> 3) & 3) * 256 + (m & 15) * 16 + (c0 & 7) * 2;
    astore8((_Float16*)((char*)hout + off), hv);
  }
}

// ---- step functions ----

template <bool DEEP>
static __device__ __attribute__((noinline)) void stepEnc0(
    int tid, int m0, int hc0, unsigned* flagsG, unsigned* myflags, int mySlot, int p,
    const float* xstep, const _Float16* h0prev, _Float16* h0out, float* creg,
    bool doInv) {
  extern __shared__ char smem[];
  int lane = tid & 63, wave = tid >> 6;
  v4f acc[4];
  acc[0] = v4f{0.f, 0.f, 0.f, 0.f}; acc[1] = acc[0]; acc[2] = acc[0]; acc[3] = acc[0];
  const char* wbLane = smem + WOFF + (size_t)lane * 16;
  xChunk(xstep, m0, tid, wbLane, acc);          // off critical path
  waitRolesPriv(myflags, p + 1, p - 2);         // h0(p-1) ready + reuse guard
  if (DEEP && doInv) acquireFence();
  mfma8<1, DEEP>(h0prev, (m0 >> 4) + wave, lane, wbLane, acc);
  epilogue(tid, m0, hc0, 0, h0out, creg, acc);
  signalDone(flagsG, mySlot, p + 2);
}

template <bool DEEP>
static __device__ __attribute__((noinline)) void stepL1(
    int tid, int m0, int hc0, unsigned* flagsG, unsigned* myflags, int mySlot,
    int tR1, int tR0,
    const _Float16* h0src, const _Float16* h1prev, _Float16* h1out, float* creg,
    bool doInv) {
  extern __shared__ char smem[];
  int lane = tid & 63, wave = tid >> 6;
  v4f acc[4];
  acc[0] = v4f{0.f, 0.f, 0.f, 0.f}; acc[1] = acc[0]; acc[2] = acc[0]; acc[3] = acc[0];
  const char* wbLane = smem + WOFF + (size_t)lane * 16;
  int rt = (m0 >> 4) + wave;
  waitRolesPriv(myflags, tR0, tR1);   // h0(cur) + h1(prev)+reuse, one poll
  if (DEEP && doInv) acquireFence();
  mfmaDual<DEEP>(h0src, h1prev, rt, lane, wbLane, acc);
  epilogue(tid, m0, hc0, 0, h1out, creg, acc);
  signalDone(flagsG, mySlot, tR0);
}

template <bool DEEP>
static __device__ __attribute__((noinline)) void stepDec0(
    int tid, int m0, int hc0, unsigned* flagsG, unsigned* myflags, int mySlot, int u,
    const _Float16* h0prev, _Float16* h0out, float* creg, bool doInv) {
  extern __shared__ char smem[];
  int lane = tid & 63, wave = tid >> 6;
  v4f acc[4];
  acc[0] = v4f{0.f, 0.f, 0.f, 0.f}; acc[1] = acc[0]; acc[2] = acc[0]; acc[3] = acc[0];
  const char* wbLane = smem + WOFF + (size_t)lane * 16;
  waitRolePriv(myflags, 0, u + 1);    // h0(t-1) ready (own role)
  if (DEEP && doInv) acquireFence();
  mfma8<0, DEEP>(h0prev, (m0 >> 4) + wave, lane, wbLane, acc);
  epilogue(tid, m0, hc0, 1, h0out, creg, acc);
  signalDone(flagsG, mySlot, u + 2);
}

template <bool DEEP>
__global__ void __launch_bounds__(256, 1)
seq2seq_kernel(const float* x,
               const float* e0wi, const float* e0wh, const float* e0bi, const float* e0bh,
               const float* e1wi, const float* e1wh, const float* e1bi, const float* e1bh,
               const float* d0wi, const float* d0wh, const float* d0bi, const float* d0bh,
               const float* d1wi, const float* d1wh, const float* d1bi, const float* d1bh,
               const float* pw, const float* pb,
               float* out, char* ws) {
  extern __shared__ char smem[];
  constexpr int D0M = DEEP ? 15 : 3;   // h0 ring mask
  constexpr int D1M = DEEP ? 15 : 1;   // h1 ring mask
  int tid = threadIdx.x, bid = blockIdx.x;
  // XCD-pair placement: bid%8 = XCD (MI355X round-robin). group g owns
  // XCDs {2g, 2g+1}; within the pair, idx*2+(xcd&1) enumerates r = 0..63.
  int xcd = bid & 7, idx = bid >> 3;
  int group = xcd >> 1;
  int r = idx * 2 + (xcd & 1);
  bool isL1 = (r >= 32);
  int hcTile = r & 31;
  int hc0 = hcTile * 16;
  int m0 = group * 64;
  unsigned* flagsG = (unsigned*)(ws + WS_BAR) + (size_t)group * 64 * 64 * 16;
  unsigned* myflags = flagsG + (size_t)r * 64 * 16;
  int mySlot = isL1 ? 32 + hcTile : hcTile;

  char* h0ring = ws + WS_HOFF;
  char* h1ring = ws + WS_HOFF + (size_t)(D0M + 1) * HBYTES;

  float creg[4];
  creg[0] = 0.f; creg[1] = 0.f; creg[2] = 0.f; creg[3] = 0.f;

  // zero the "step -1" ring slots (h0 slot D0M, h1 slot D1M), group slice
  {
    int t16 = r * 256 + tid;
    char* base = (t16 < 8192) ? (h0ring + (size_t)D0M * HBYTES)
                              : (h1ring + (size_t)D1M * HBYTES);
    int idx8 = t16 & 8191;
    astore8z(base + (size_t)m0 * HHD * 2 + (size_t)idx8 * 8);
  }

  if (!isL1) {
    loadWeights(tid, hc0, e0wi, 64, 64, e0wh, 576);
    if (tid < 64) {
      int n = (tid >> 4) * HHD + hc0 + (tid & 15);
      ((float*)(smem + BIAS_OFF))[tid] = e0bi[n] + e0bh[n];
    }
  } else {
    loadWeights(tid, hc0, e1wi, 512, 512, e1wh, 1024);
    if (tid < 64) {
      int n = (tid >> 4) * HHD + hc0 + (tid & 15);
      ((float*)(smem + BIAS_OFF))[tid] = e1bi[n] + e1bh[n];
    }
  }
  signalDone(flagsG, mySlot, 1);

  if (!isL1) {
    // ---------------- encoder layer 0 ----------------
    for (int p = 0; p < TINN; ++p)
      stepEnc0<DEEP>(tid, m0, hc0, flagsG, myflags, mySlot, p,
                     x + (size_t)p * FF,
                     (const _Float16*)(h0ring + (size_t)((p + D0M) & D0M) * HBYTES),
                     (_Float16*)(h0ring + (size_t)(p & D0M) * HBYTES),
                     creg, (p % INV_PERIOD) == 0);
    // ---------------- decoder layer 0 ----------------
    loadWeights(tid, hc0, d0wh, 512, 512, nullptr, 512);
    if (tid < 64) {
      int n = (tid >> 4) * HHD + hc0 + (tid & 15);
      ((float*)(smem + BIAS_OFF))[tid] = d0bi[n] + d0bh[n];
      ((float*)(smem + WIH0_OFF))[tid] = d0wi[n];
    }
    for (int k = tid; k < 512; k += 256) ((float*)(smem + PROJW_OFF))[k] = pw[k];
    if (tid == 0) ((float*)(smem + PROJB_OFF))[0] = pb[0];
    for (int t = 0; t <= TOUTN; ++t) {
      int u = TINN + t;
      waitRolePriv(myflags, 32, u + 1);   // h1(t-1) ready
      float* prevl = (float*)(smem + PREV_OFF);
      if (t == 0) {
        if (tid < 64)
          prevl[tid] = x[(size_t)(m0 + tid) * (TINN * FF) + 511 * 64 + 63];
      } else {
        float* part = (float*)(smem + PART_OFF);
        float* pjw = (float*)(smem + PROJW_OFF);
        const _Float16* h1base =
            (const _Float16*)(h1ring + (size_t)((u + D1M) & D1M) * HBYTES);
        int m = m0 + (tid >> 2);
        int rt = m >> 4, l15m = m & 15;
        int kc0 = (tid & 3) * 2;
        float s = 0.f;
#pragma unroll
        for (int kc = kc0; kc < kc0 + 2; ++kc)
#pragma unroll
          for (int ks = 0; ks < 2; ++ks)
#pragma unroll
            for (int q = 0; q < 4; ++q) {
              int off = (rt * 8 + kc) * 2048 + ks * 1024 + q * 256 + l15m * 16;
              v8h hv = aload16(h1base + off / 2);
              const float* w = pjw + kc * 64 + ks * 32 + q * 8;
#pragma unroll
              for (int e = 0; e < 8; ++e) s += (float)hv[e] * w[e];
            }
        part[tid] = s;
        __syncthreads();
        if (tid < 64) {
          float p4 = part[tid * 4] + part[tid * 4 + 1] + part[tid * 4 + 2] +
                     part[tid * 4 + 3] + ((float*)(smem + PROJB_OFF))[0];
          prevl[tid] = p4;
          if (hcTile == 0) out[(size_t)(m0 + tid) * TOUTN + (t - 1)] = p4;
        }
      }
      __syncthreads();
      if (t < TOUTN)
        stepDec0<DEEP>(tid, m0, hc0, flagsG, myflags, mySlot, u,
                       (const _Float16*)(h0ring + (size_t)((u + D0M) & D0M) * HBYTES),
                       (_Float16*)(h0ring + (size_t)(u & D0M) * HBYTES),
                       creg, (u % INV_PERIOD) == 0);
    }
  } else {
    // ---------------- encoder layer 1 ----------------
    for (int s = 0; s < TINN; ++s)
      stepL1<DEEP>(tid, m0, hc0, flagsG, myflags, mySlot, s + 1, s + 2,
                   (const _Float16*)(h0ring + (size_t)(s & D0M) * HBYTES),
                   (const _Float16*)(h1ring + (size_t)((s + D1M) & D1M) * HBYTES),
                   (_Float16*)(h1ring + (size_t)(s & D1M) * HBYTES),
                   creg, (s % INV_PERIOD) == 0);
    // ---------------- decoder layer 1 ----------------
    loadWeights(tid, hc0, d1wi, 512, 512, d1wh, 1024);
    if (tid < 64) {
      int n = (tid >> 4) * HHD + hc0 + (tid & 15);
      ((float*)(smem + BIAS_OFF))[tid] = d1bi[n] + d1bh[n];
    }
    for (int t = 0; t < TOUTN; ++t) {
      int u = TINN + t;
      stepL1<DEEP>(tid, m0, hc0, flagsG, myflags, mySlot, u + 1, u + 2,
                   (const _Float16*)(h0ring + (size_t)(u & D0M) * HBYTES),
                   (const _Float16*)(h1ring + (size_t)((u + D1M) & D1M) * HBYTES),
                   (_Float16*)(h1ring + (size_t)(u & D1M) * HBYTES),
                   creg, (u % INV_PERIOD) == 0);
    }
  }
}

extern "C" void kernel_launch(void* const* d_in, const int* in_sizes, int n_in,
                              void* d_out, int out_size, void* d_ws, size_t ws_size,
                              hipStream_t stream) {
  const float* x = (const float*)d_in[0];
  const float* e0wi = (const float*)d_in[2];
  const float* e0wh = (const float*)d_in[3];
  const float* e0bi = (const float*)d_in[4];
  const float* e0bh = (const float*)d_in[5];
  const float* e1wi = (const float*)d_in[6];
  const float* e1wh = (const float*)d_in[7];
  const float* e1bi = (const float*)d_in[8];
  const float* e1bh = (const float*)d_in[9];
  const float* d0wi = (const float*)d_in[10];
  const float* d0wh = (const float*)d_in[11];
  const float* d0bi = (const float*)d_in[12];
  const float* d0bh = (const float*)d_in[13];
  const float* d1wi = (const float*)d_in[14];
  const float* d1wh = (const float*)d_in[15];
  const float* d1bi = (const float*)d_in[16];
  const float* d1bh = (const float*)d_in[17];
  const float* pw = (const float*)d_in[18];
  const float* pb = (const float*)d_in[19];

  bool deep = (ws_size >= WS_NEED_DEEP);
  (void)hipMemsetAsync(d_ws, 0, WS_FLAG_BYTES, stream);  // replicated flags
  if (deep) {
    (void)hipFuncSetAttribute((const void*)seq2seq_kernel<true>,
                              hipFuncAttributeMaxDynamicSharedMemorySize, SMEM_TOTAL);
    seq2seq_kernel<true><<<dim3(256), dim3(256), SMEM_TOTAL, stream>>>(
        x, e0wi, e0wh, e0bi, e0bh, e1wi, e1wh, e1bi, e1bh,
        d0wi, d0wh, d0bi, d0bh, d1wi, d1wh, d1bi, d1bh,
        pw, pb, (float*)d_out, (char*)d_ws);
  } else {
    (void)hipFuncSetAttribute((const void*)seq2seq_kernel<false>,
                              hipFuncAttributeMaxDynamicSharedMemorySize, SMEM_TOTAL);
    seq2seq_kernel<false><<<dim3(256), dim3(256), SMEM_TOTAL, stream>>>(
        x, e0wi, e0wh, e0bi, e0bh, e1wi, e1wh, e1bi, e1bh,
        d0wi, d0wh, d0bi, d0bh, d1wi, d1wh, d1bi, d1bh,
        pw, pb, (float*)d_out, (char*)d_ws);
  }
}

// Round 7
// 4572.323 us; speedup vs baseline: 1.0385x; 1.0385x over previous
//
#include <hip/hip_runtime.h>

#define TINN 512
#define FF 64
#define HHD 512
#define TOUTN 64

using v8h = __attribute__((ext_vector_type(8))) _Float16;
using v4h = __attribute__((ext_vector_type(4))) _Float16;
using v4f = __attribute__((ext_vector_type(4))) float;
using u32x4 = __attribute__((ext_vector_type(4))) unsigned int;
using u64 = unsigned long long;

#define AGT __HIP_MEMORY_SCOPE_AGENT

// ---------------- LDS layout (bytes) ----------------
#define WOFF 0            // weights, MFMA fragment order (max 128KB)
#define BIAS_OFF 131072
#define WIH0_OFF 131328
#define PREV_OFF 131584
#define PART_OFF 131840
#define PROJW_OFF 132864
#define PROJB_OFF 134912
#define TRANS_OFF 134976  // 4 waves x 512B h-transpose scratch
#define XCD_OFF 137024    // 64 ints: census (XCD per group block)
#define FL_OFF 137280     // 64 chars: per-consumer flag-local policy
#define SMEM_TOTAL 137344

// ---------------- workspace layout ----------------
// Replicated flags, census, then h rings in TWO mirrors:
//   LOCAL mirror: NORMAL stores (write-back -> producer's L2) + sc0 loads
//     (bypass L1, hit L2). Used only when the census proves ALL producers
//     of that role share the consumer's XCD. ~0.2us hops instead of ~1.2us.
//   REMOTE mirror: cache-bypass (sc0|sc1) atomics at the LLC — the proven
//     R3 protocol, for any cross-XCD edge.
// Policy consistency: the poll/data policy for role-R lines is the
// AGGREGATE myLocR = AND_{j in role R}(XCD(j)==XCD(me)), computable
// identically by producers (for each consumer) and consumers -> a consumer
// that reads the remote mirror is only ever released by the remote flag
// (raised after vmcnt(0), i.e., after the remote data store is acked).
// Split-ack: vmcnt(1) acks the LOCAL h store -> local flags (normal store);
// vmcnt(0) acks the remote store -> remote flags (bypass). Dirty-L2 lines
// never cross kernel launches (dispatch-boundary release flushes L2).
#define WS_FLAG_BYTES (4 * 64 * 64 * 64)   // 1 MiB
#define WS_CENSUS WS_FLAG_BYTES
#define WS_CENSUS_BYTES (4 * 64 * 64)      // 16 KiB
#define WS_HOFF (WS_FLAG_BYTES + WS_CENSUS_BYTES)
#define HBYTES (256 * HHD * 2)             // 256 KiB per ring slot
// local mirror slots 0..5, remote mirror slots 6..11
// (h0 ring = slots 0..3, h1 ring = slots 4..5 within each mirror)

static __device__ __forceinline__ float sigm(float x) { return 1.0f / (1.0f + __expf(-x)); }
static __device__ __forceinline__ float tanh_f(float x) { return 1.0f - 2.0f / (1.0f + __expf(2.0f * x)); }

static __device__ __forceinline__ void schedBar() {
#if __has_builtin(__builtin_amdgcn_sched_barrier)
  __builtin_amdgcn_sched_barrier(0);
#endif
}

static __device__ __forceinline__ v8h aload16(const _Float16* p) {
  union { u64 u[2]; v8h h; } c;
  const u64* q = (const u64*)p;
  c.u[0] = __hip_atomic_load(q, __ATOMIC_RELAXED, AGT);
  c.u[1] = __hip_atomic_load(q + 1, __ATOMIC_RELAXED, AGT);
  return c.h;
}
static __device__ __forceinline__ void astore8(_Float16* p, v4h v) {
  union { u64 u; v4h h; } c;
  c.h = v;
  __hip_atomic_store((u64*)p, c.u, __ATOMIC_RELAXED, AGT);
}
static __device__ __forceinline__ void astore8z(void* p) {
  __hip_atomic_store((u64*)p, 0ull, __ATOMIC_RELAXED, AGT);
}

#if __has_builtin(__builtin_amdgcn_raw_ptr_buffer_load_b128) && \
    __has_builtin(__builtin_amdgcn_make_buffer_rsrc)
#define HAVE_BUFLOAD 1
using rsrc_t = __amdgpu_buffer_rsrc_t;
static __device__ __forceinline__ rsrc_t mkrsrc(const void* p) {
  return __builtin_amdgcn_make_buffer_rsrc((void*)p, (short)0, 0xFFFFFFFFu, 0x00020000);
}
static __device__ __forceinline__ v8h bload16_b(rsrc_t r, int byteOff) {  // LLC bypass
  union { u32x4 u; v8h h; } c;
  c.u = __builtin_amdgcn_raw_ptr_buffer_load_b128(r, byteOff, 0, 17);  // sc0|sc1
  return c.h;
}
static __device__ __forceinline__ v8h bload16_l(rsrc_t r, int byteOff) {  // L2 (sc0)
  union { u32x4 u; v8h h; } c;
  c.u = __builtin_amdgcn_raw_ptr_buffer_load_b128(r, byteOff, 0, 1);   // sc0
  return c.h;
}
// sc0 32-bit flag read via the proven b128 builtin (flags are 64B-strided).
static __device__ __forceinline__ unsigned flagLoadL2(const unsigned* p) {
  union { u32x4 u; } c;
  c.u = __builtin_amdgcn_raw_ptr_buffer_load_b128(mkrsrc(p), 0, 0, 1);  // sc0
  return c.u[0];
}
#else
#define HAVE_BUFLOAD 0
#endif

// XCD id of the CU this block runs on. [measured: learn_hip m09 on MI355X]
static __device__ __forceinline__ int getXcc() {
  int x;
  asm volatile("s_getreg_b32 %0, hwreg(HW_REG_XCC_ID)" : "=s"(x));
  return x & 15;
}

// ---- signaling ----
// vmcnt(1): local (normal) h store acked at L2 -> local flags (normal
// stores into the producer's L2; same-XCD consumers read them with sc0).
// vmcnt(0): remote (bypass) h store acked at LLC -> remote flags (bypass).
static __device__ __forceinline__ void signalStep(
    unsigned* flagsG, int mySlot, unsigned val, const char* flagLoc) {
  asm volatile("s_waitcnt vmcnt(1) lgkmcnt(0)" ::: "memory");
  schedBar();
  __builtin_amdgcn_s_barrier();
  int t = threadIdx.x;
  bool lane = t < 64;
  bool fl = lane && (flagLoc[t & 63] != 0);
  unsigned* p = flagsG + ((size_t)(t & 63) * 64 + mySlot) * 16;
  if (fl) *p = val;                         // normal store -> my L2
  asm volatile("s_waitcnt vmcnt(0) lgkmcnt(0)" ::: "memory");
  schedBar();
  __builtin_amdgcn_s_barrier();
  if (lane && !fl)
    __hip_atomic_store(p, val, __ATOMIC_RELAXED, AGT);   // bypass -> LLC
}
static __device__ __forceinline__ void signalInit(
    unsigned* flagsG, int mySlot, unsigned val, const char* flagLoc) {
  asm volatile("s_waitcnt vmcnt(0) lgkmcnt(0)" ::: "memory");
  schedBar();
  signalStep(flagsG, mySlot, val, flagLoc);
}

// Spin on one flag. loc -> sc0 (L2) read; else bypass atomic (LLC).
// The empty asm with a memory clobber forces the load to re-execute each
// iteration (hang-proof: intrinsic loads are otherwise hoistable).
static __device__ __forceinline__ void pollSlot(unsigned* p, int tgt, bool loc) {
  for (;;) {
    unsigned v;
#if HAVE_BUFLOAD
    if (loc) v = flagLoadL2(p);
    else
#endif
      v = __hip_atomic_load(p, __ATOMIC_RELAXED, AGT);
    if ((int)v >= tgt) break;
    asm volatile("" ::: "memory");
    __builtin_amdgcn_s_sleep(1);
  }
}

// Dual-role poll: lanes 0-31 poll role0 (tgt0, policy loc0), 32-63 role1.
static __device__ __forceinline__ void waitRolesPriv(
    unsigned* myflags, int tgt0, int tgt1, bool loc0, bool loc1) {
  int t = threadIdx.x;
  if (t < 64) {
    int tgt = (t < 32) ? tgt0 : tgt1;
    if (tgt > 0)
      pollSlot(myflags + (size_t)t * 16, tgt, (t < 32) ? loc0 : loc1);
  }
  __syncthreads();
  schedBar();
}
static __device__ __forceinline__ void waitRolePriv(
    unsigned* myflags, int base, int tgt, bool loc) {
  if (tgt > 0) {
    int t = threadIdx.x;
    if (t < 32)
      pollSlot(myflags + (size_t)(base + t) * 16, tgt, loc);
    __syncthreads();
    schedBar();
  }
}

// Weight slice (64 gate-cols x K) fp32->fp16 into LDS, fragment order.
static __device__ __attribute__((noinline)) void loadWeights(
    int tid, int hc0, const float* W1, int ld1, int K1,
    const float* W2, int K) {
  extern __shared__ char smem[];
  int c = tid >> 2, sub = tid & 3;
  int nt = c >> 4, l = c & 15;
  int n = nt * HHD + hc0 + l;
  int Kq = K >> 2;
  for (int k = sub * Kq; k < (sub + 1) * Kq; ++k) {
    float v;
    if (k < K1) v = W1[(size_t)n * ld1 + k];
    else        v = W2[(size_t)n * HHD + (k - K1)];
    int kc = k >> 6, ks = (k >> 5) & 1, quad = (k >> 3) & 3, j = k & 7;
    int off = (((kc * 2 + ks) * 4 + nt) * 64 + quad * 16 + l) * 16 + j * 2;
    *(_Float16*)(smem + WOFF + off) = (_Float16)v;
  }
}

// 8 K-chunks of MFMA; LOCAL selects sc0 (L2) vs bypass (LLC) loads.
template <int WC0, bool LOCAL>
static __device__ __forceinline__ void mfma8(
    const _Float16* src, int rt, int lane, const char* wbLane, v4f* acc) {
#if HAVE_BUFLOAD
  rsrc_t rs = mkrsrc(src);
#endif
#pragma unroll
  for (int kc = 0; kc < 8; ++kc) {
    int off = rt * 16384 + kc * 2048 + lane * 16;
    v8h ak0, ak1;
#if HAVE_BUFLOAD
    if constexpr (LOCAL) { ak0 = bload16_l(rs, off); ak1 = bload16_l(rs, off + 1024); }
    else                 { ak0 = bload16_b(rs, off); ak1 = bload16_b(rs, off + 1024); }
#else
    ak0 = aload16(src + off / 2);
    ak1 = aload16(src + (off + 1024) / 2);
#endif
    const char* bb = wbLane + (size_t)(WC0 + kc) * 8192;
#pragma unroll
    for (int ks = 0; ks < 2; ++ks) {
      v8h a = ks ? ak1 : ak0;
      acc[0] = __builtin_amdgcn_mfma_f32_16x16x32_f16(a, *(const v8h*)(bb + (ks * 4 + 0) * 1024), acc[0], 0, 0, 0);
      acc[1] = __builtin_amdgcn_mfma_f32_16x16x32_f16(a, *(const v8h*)(bb + (ks * 4 + 1) * 1024), acc[1], 0, 0, 0);
      acc[2] = __builtin_amdgcn_mfma_f32_16x16x32_f16(a, *(const v8h*)(bb + (ks * 4 + 2) * 1024), acc[2], 0, 0, 0);
      acc[3] = __builtin_amdgcn_mfma_f32_16x16x32_f16(a, *(const v8h*)(bb + (ks * 4 + 3) * 1024), acc[3], 0, 0, 0);
    }
  }
}

// Fused double-source MFMA for stepL1: all 32 A-loads (h1 then h0) issued
// before any MFMA. h1 -> weight chunks 8..15, h0 -> weight chunks 0..7.
template <bool LOC0, bool LOC1>
static __device__ __forceinline__ void mfmaDual(
    const _Float16* h0src, const _Float16* h1src, int rt, int lane,
    const char* wbLane, v4f* acc) {
  v8h a1[16], a0[16];
#if HAVE_BUFLOAD
  rsrc_t r1 = mkrsrc(h1src);
  rsrc_t r0 = mkrsrc(h0src);
#pragma unroll
  for (int kc = 0; kc < 8; ++kc) {
    int off = rt * 16384 + kc * 2048 + lane * 16;
    if constexpr (LOC1) { a1[2 * kc] = bload16_l(r1, off); a1[2 * kc + 1] = bload16_l(r1, off + 1024); }
    else                { a1[2 * kc] = bload16_b(r1, off); a1[2 * kc + 1] = bload16_b(r1, off + 1024); }
  }
#pragma unroll
  for (int kc = 0; kc < 8; ++kc) {
    int off = rt * 16384 + kc * 2048 + lane * 16;
    if constexpr (LOC0) { a0[2 * kc] = bload16_l(r0, off); a0[2 * kc + 1] = bload16_l(r0, off + 1024); }
    else                { a0[2 * kc] = bload16_b(r0, off); a0[2 * kc + 1] = bload16_b(r0, off + 1024); }
  }
#else
#pragma unroll
  for (int kc = 0; kc < 8; ++kc) {
    int off = rt * 16384 + kc * 2048 + lane * 16;
    a1[2 * kc]     = aload16(h1src + off / 2);
    a1[2 * kc + 1] = aload16(h1src + (off + 1024) / 2);
  }
#pragma unroll
  for (int kc = 0; kc < 8; ++kc) {
    int off = rt * 16384 + kc * 2048 + lane * 16;
    a0[2 * kc]     = aload16(h0src + off / 2);
    a0[2 * kc + 1] = aload16(h0src + (off + 1024) / 2);
  }
#endif
#pragma unroll
  for (int kc = 0; kc < 8; ++kc) {
    const char* bb = wbLane + (size_t)(8 + kc) * 8192;
#pragma unroll
    for (int ks = 0; ks < 2; ++ks) {
      v8h a = a1[2 * kc + ks];
      acc[0] = __builtin_amdgcn_mfma_f32_16x16x32_f16(a, *(const v8h*)(bb + (ks * 4 + 0) * 1024), acc[0], 0, 0, 0);
      acc[1] = __builtin_amdgcn_mfma_f32_16x16x32_f16(a, *(const v8h*)(bb + (ks * 4 + 1) * 1024), acc[1], 0, 0, 0);
      acc[2] = __builtin_amdgcn_mfma_f32_16x16x32_f16(a, *(const v8h*)(bb + (ks * 4 + 2) * 1024), acc[2], 0, 0, 0);
      acc[3] = __builtin_amdgcn_mfma_f32_16x16x32_f16(a, *(const v8h*)(bb + (ks * 4 + 3) * 1024), acc[3], 0, 0, 0);
    }
  }
#pragma unroll
  for (int kc = 0; kc < 8; ++kc) {
    const char* bb = wbLane + (size_t)kc * 8192;
#pragma unroll
    for (int ks = 0; ks < 2; ++ks) {
      v8h a = a0[2 * kc + ks];
      acc[0] = __builtin_amdgcn_mfma_f32_16x16x32_f16(a, *(const v8h*)(bb + (ks * 4 + 0) * 1024), acc[0], 0, 0, 0);
      acc[1] = __builtin_amdgcn_mfma_f32_16x16x32_f16(a, *(const v8h*)(bb + (ks * 4 + 1) * 1024), acc[1], 0, 0, 0);
      acc[2] = __builtin_amdgcn_mfma_f32_16x16x32_f16(a, *(const v8h*)(bb + (ks * 4 + 2) * 1024), acc[2], 0, 0, 0);
      acc[3] = __builtin_amdgcn_mfma_f32_16x16x32_f16(a, *(const v8h*)(bb + (ks * 4 + 3) * 1024), acc[3], 0, 0, 0);
    }
  }
}

// x chunk (weight chunk 0): raw fp32 x, cached (read-only).
static __device__ __forceinline__ void xChunk(
    const float* xstep, int m0, int tid, const char* wbLane, v4f* acc) {
  int lane = tid & 63, wave = tid >> 6;
  int l15 = lane & 15, quad = lane >> 4;
  v8h ak0, ak1;
  int ra = m0 + wave * 16 + l15;
  const float* xr = xstep + (size_t)ra * (TINN * FF) + quad * 8;
  v4f f00 = *(const v4f*)(xr);
  v4f f01 = *(const v4f*)(xr + 4);
  v4f f10 = *(const v4f*)(xr + 32);
  v4f f11 = *(const v4f*)(xr + 36);
#pragma unroll
  for (int e = 0; e < 4; ++e) {
    ak0[e] = (_Float16)f00[e]; ak0[4 + e] = (_Float16)f01[e];
    ak1[e] = (_Float16)f10[e]; ak1[4 + e] = (_Float16)f11[e];
  }
#pragma unroll
  for (int ks = 0; ks < 2; ++ks) {
    v8h a = ks ? ak1 : ak0;
    acc[0] = __builtin_amdgcn_mfma_f32_16x16x32_f16(a, *(const v8h*)(wbLane + (ks * 4 + 0) * 1024), acc[0], 0, 0, 0);
    acc[1] = __builtin_amdgcn_mfma_f32_16x16x32_f16(a, *(const v8h*)(wbLane + (ks * 4 + 1) * 1024), acc[1], 0, 0, 0);
    acc[2] = __builtin_amdgcn_mfma_f32_16x16x32_f16(a, *(const v8h*)(wbLane + (ks * 4 + 2) * 1024), acc[2], 0, 0, 0);
    acc[3] = __builtin_amdgcn_mfma_f32_16x16x32_f16(a, *(const v8h*)(wbLane + (ks * 4 + 3) * 1024), acc[3], 0, 0, 0);
  }
}

// Gate math + wave-local LDS transpose + DUAL h store: normal store to the
// LOCAL mirror first (acked by vmcnt(1)), bypass store to the REMOTE
// mirror second (acked by vmcnt(0)). sched_barrier pins the issue order.
static __device__ __forceinline__ void epilogue(
    int tid, int m0, int hc0, int rank1, _Float16* houtL, _Float16* houtR,
    float* creg, v4f* acc) {
  extern __shared__ char smem[];
  int lane = tid & 63, wave = tid >> 6;
  int l15 = lane & 15, quad = lane >> 4;
  float* bias = (float*)(smem + BIAS_OFF);
  float bi = bias[l15], bf = bias[16 + l15], bg = bias[32 + l15], bo = bias[48 + l15];
  float wi = 0.f, wf = 0.f, wg = 0.f, wo = 0.f;
  if (rank1) {
    float* wih0 = (float*)(smem + WIH0_OFF);
    wi = wih0[l15]; wf = wih0[16 + l15]; wg = wih0[32 + l15]; wo = wih0[48 + l15];
  }
  float* prevl = (float*)(smem + PREV_OFF);
  _Float16* tb = (_Float16*)(smem + TRANS_OFF + (size_t)wave * 512);
#pragma unroll
  for (int r = 0; r < 4; ++r) {
    int mloc = wave * 16 + quad * 4 + r;
    float gi = acc[0][r] + bi, gf = acc[1][r] + bf;
    float gg = acc[2][r] + bg, go = acc[3][r] + bo;
    if (rank1) {
      float pv = prevl[mloc];
      gi += pv * wi; gf += pv * wf; gg += pv * wg; go += pv * wo;
    }
    float cc = sigm(gf) * creg[r] + sigm(gi) * tanh_f(gg);
    float h = sigm(go) * tanh_f(cc);
    creg[r] = cc;
    tb[(quad * 4 + r) * 16 + l15] = (_Float16)h;   // m-fast deposit
  }
  {
    int mloc = lane & 15, cg = lane >> 4;
    v4h hv = *(const v4h*)(tb + mloc * 16 + cg * 4);
    int m = m0 + wave * 16 + mloc;
    int c0 = hc0 + cg * 4;
    int off = (m >> 4) * 16384 + (c0 >> 6) * 2048 + ((c0 >> 5) & 1) * 1024 +
              ((c0 >> 3) & 3) * 256 + (m & 15) * 16 + (c0 & 7) * 2;
    *(v4h*)((char*)houtL + off) = hv;          // normal -> my L2
    schedBar();
    astore8((_Float16*)((char*)houtR + off), hv);  // bypass -> LLC
  }
}

// ---- step functions ----

static __device__ __attribute__((noinline)) void stepEnc0(
    int tid, int m0, int hc0, unsigned* flagsG, unsigned* myflags, int mySlot, int p,
    const float* xstep, const _Float16* h0prev, _Float16* h0outL, _Float16* h0outR,
    float* creg, const char* flagLoc, bool loc0, bool loc1) {
  extern __shared__ char smem[];
  int lane = tid & 63, wave = tid >> 6;
  v4f acc[4];
  acc[0] = v4f{0.f, 0.f, 0.f, 0.f}; acc[1] = acc[0]; acc[2] = acc[0]; acc[3] = acc[0];
  const char* wbLane = smem + WOFF + (size_t)lane * 16;
  xChunk(xstep, m0, tid, wbLane, acc);               // off critical path
  waitRolesPriv(myflags, p + 1, p - 2, loc0, loc1);  // h0(p-1) + reuse guard
  int rt = (m0 >> 4) + wave;
  if (loc0) mfma8<1, true >(h0prev, rt, lane, wbLane, acc);
  else      mfma8<1, false>(h0prev, rt, lane, wbLane, acc);
  epilogue(tid, m0, hc0, 0, h0outL, h0outR, creg, acc);
  signalStep(flagsG, mySlot, p + 2, flagLoc);
}

static __device__ __attribute__((noinline)) void stepL1(
    int tid, int m0, int hc0, unsigned* flagsG, unsigned* myflags, int mySlot,
    int tR1, int tR0,
    const _Float16* h0src, const _Float16* h1prev,
    _Float16* h1outL, _Float16* h1outR, float* creg,
    const char* flagLoc, bool loc0, bool loc1) {
  extern __shared__ char smem[];
  int lane = tid & 63, wave = tid >> 6;
  v4f acc[4];
  acc[0] = v4f{0.f, 0.f, 0.f, 0.f}; acc[1] = acc[0]; acc[2] = acc[0]; acc[3] = acc[0];
  const char* wbLane = smem + WOFF + (size_t)lane * 16;
  int rt = (m0 >> 4) + wave;
  waitRolesPriv(myflags, tR0, tR1, loc0, loc1);
  if (loc0) {
    if (loc1) mfmaDual<true,  true >(h0src, h1prev, rt, lane, wbLane, acc);
    else      mfmaDual<true,  false>(h0src, h1prev, rt, lane, wbLane, acc);
  } else {
    if (loc1) mfmaDual<false, true >(h0src, h1prev, rt, lane, wbLane, acc);
    else      mfmaDual<false, false>(h0src, h1prev, rt, lane, wbLane, acc);
  }
  epilogue(tid, m0, hc0, 0, h1outL, h1outR, creg, acc);
  signalStep(flagsG, mySlot, tR0, flagLoc);
}

static __device__ __attribute__((noinline)) void stepDec0(
    int tid, int m0, int hc0, unsigned* flagsG, unsigned* myflags, int mySlot, int u,
    const _Float16* h0prev, _Float16* h0outL, _Float16* h0outR, float* creg,
    const char* flagLoc, bool loc0) {
  extern __shared__ char smem[];
  int lane = tid & 63, wave = tid >> 6;
  v4f acc[4];
  acc[0] = v4f{0.f, 0.f, 0.f, 0.f}; acc[1] = acc[0]; acc[2] = acc[0]; acc[3] = acc[0];
  const char* wbLane = smem + WOFF + (size_t)lane * 16;
  waitRolePriv(myflags, 0, u + 1, loc0);   // h0(t-1) ready (own role)
  int rt = (m0 >> 4) + wave;
  if (loc0) mfma8<0, true >(h0prev, rt, lane, wbLane, acc);
  else      mfma8<0, false>(h0prev, rt, lane, wbLane, acc);
  epilogue(tid, m0, hc0, 1, h0outL, h0outR, creg, acc);
  signalStep(flagsG, mySlot, u + 2, flagLoc);
}

__global__ void __launch_bounds__(256, 1)
seq2seq_kernel(const float* x,
               const float* e0wi, const float* e0wh, const float* e0bi, const float* e0bh,
               const float* e1wi, const float* e1wh, const float* e1bi, const float* e1bh,
               const float* d0wi, const float* d0wh, const float* d0bi, const float* d0bh,
               const float* d1wi, const float* d1wh, const float* d1bi, const float* d1bh,
               const float* pw, const float* pb,
               float* out, char* ws) {
  extern __shared__ char smem[];
  int tid = threadIdx.x, bid = blockIdx.x;
  // Target placement (if dispatch round-robins bid%8 over XCDs): group g's
  // role0 on XCD 2g, role1 on XCD 2g+1. The census ADAPTS to the real
  // mapping; a wrong guess only costs performance, never correctness.
  int xcd8 = bid & 7, idx = bid >> 3;
  int group = xcd8 >> 1;
  int r = (xcd8 & 1) * 32 + idx;
  bool isL1 = (r >= 32);
  int hcTile = r & 31;
  int hc0 = hcTile * 16;
  int m0 = group * 64;
  unsigned* flagsG = (unsigned*)ws + (size_t)group * 64 * 64 * 16;
  unsigned* myflags = flagsG + (size_t)r * 64 * 16;
  int mySlot = isL1 ? 32 + hcTile : hcTile;

  char* hb = ws + WS_HOFF;

  float creg[4];
  creg[0] = 0.f; creg[1] = 0.f; creg[2] = 0.f; creg[3] = 0.f;

  // zero the "step -1" ring slots (h0 slot 3, h1 slot 5) in BOTH mirrors.
  {
    int t16 = r * 256 + tid;
    int slot = (t16 < 8192) ? 3 : 5;
    int idx8 = t16 & 8191;
    size_t o = (size_t)m0 * HHD * 2 + (size_t)idx8 * 8;
    astore8z(hb + (size_t)slot * HBYTES + o);
    astore8z(hb + (size_t)(6 + slot) * HBYTES + o);
  }

  // -------- XCD census: learn the REAL block->XCD mapping --------
  int myXcd = getXcc();
  {
    unsigned* census = (unsigned*)(ws + WS_CENSUS) + (size_t)group * 64 * 16;
    if (tid == 0)
      __hip_atomic_store(&census[(size_t)r * 16], (unsigned)(myXcd | 256),
                         __ATOMIC_RELAXED, AGT);
    int* sX = (int*)(smem + XCD_OFF);
    if (tid < 64) {
      unsigned v;
      unsigned* p = &census[(size_t)tid * 16];
      for (;;) {
        v = __hip_atomic_load(p, __ATOMIC_RELAXED, AGT);
        if (v & 256) break;
        __builtin_amdgcn_s_sleep(1);
      }
      sX[tid] = (int)(v & 255);
    }
    __syncthreads();
  }
  const int* sX = (const int*)(smem + XCD_OFF);
  // Aggregate locality (poll + data policy), identical on both sides:
  bool loc0 = true, loc1 = true;
  for (int i = 0; i < 32; ++i)  loc0 = loc0 && (sX[i] == myXcd);
  for (int i = 32; i < 64; ++i) loc1 = loc1 && (sX[i] == myXcd);
  {
    int cnt = 0;
    for (int i = 0; i < 64; ++i) cnt += (sX[i] == myXcd) ? 1 : 0;
    if (cnt > 32) { loc0 = false; loc1 = false; }  // >32 blk/XCD impossible
  }
#if !HAVE_BUFLOAD
  loc0 = false; loc1 = false;
#endif
  // Producer-side per-consumer flag policy: for MY role's lines, consumer c
  // is local iff ALL my-role producers share c's XCD (same aggregate).
  {
    char* fl = (char*)(smem + FL_OFF);
    if (tid < 64) {
      int lo = isL1 ? 32 : 0, hi = isL1 ? 64 : 32;
      bool f = true;
      for (int j = lo; j < hi; ++j) f = f && (sX[j] == sX[tid]);
#if !HAVE_BUFLOAD
      f = false;
#endif
      fl[tid] = f ? 1 : 0;
    }
    __syncthreads();
  }
  const char* flagLoc = (const char*)(smem + FL_OFF);

  if (!isL1) {
    loadWeights(tid, hc0, e0wi, 64, 64, e0wh, 576);
    if (tid < 64) {
      int n = (tid >> 4) * HHD + hc0 + (tid & 15);
      ((float*)(smem + BIAS_OFF))[tid] = e0bi[n] + e0bh[n];
    }
  } else {
    loadWeights(tid, hc0, e1wi, 512, 512, e1wh, 1024);
    if (tid < 64) {
      int n = (tid >> 4) * HHD + hc0 + (tid & 15);
      ((float*)(smem + BIAS_OFF))[tid] = e1bi[n] + e1bh[n];
    }
  }
  signalInit(flagsG, mySlot, 1, flagLoc);

  if (!isL1) {
    // ---------------- encoder layer 0 ----------------
    for (int p = 0; p < TINN; ++p) {
      int sp = (p + 3) & 3, so = p & 3;
      const _Float16* h0prev =
          (const _Float16*)(hb + (size_t)(loc0 ? sp : 6 + sp) * HBYTES);
      stepEnc0(tid, m0, hc0, flagsG, myflags, mySlot, p, x + (size_t)p * FF,
               h0prev,
               (_Float16*)(hb + (size_t)so * HBYTES),
               (_Float16*)(hb + (size_t)(6 + so) * HBYTES),
               creg, flagLoc, loc0, loc1);
    }
    // ---------------- decoder layer 0 ----------------
    loadWeights(tid, hc0, d0wh, 512, 512, nullptr, 512);
    if (tid < 64) {
      int n = (tid >> 4) * HHD + hc0 + (tid & 15);
      ((float*)(smem + BIAS_OFF))[tid] = d0bi[n] + d0bh[n];
      ((float*)(smem + WIH0_OFF))[tid] = d0wi[n];
    }
    for (int k = tid; k < 512; k += 256) ((float*)(smem + PROJW_OFF))[k] = pw[k];
    if (tid == 0) ((float*)(smem + PROJB_OFF))[0] = pb[0];
    __syncthreads();
    for (int t = 0; t <= TOUTN; ++t) {
      int u = TINN + t;
      waitRolePriv(myflags, 32, u + 1, loc1);   // h1(t-1) ready
      float* prevl = (float*)(smem + PREV_OFF);
      if (t == 0) {
        if (tid < 64)
          prevl[tid] = x[(size_t)(m0 + tid) * (TINN * FF) + 511 * 64 + 63];
      } else {
        float* part = (float*)(smem + PART_OFF);
        float* pjw = (float*)(smem + PROJW_OFF);
        const _Float16* h1base =
            (const _Float16*)(hb + (size_t)(6 + 4 + ((u + 1) & 1)) * HBYTES);
        int m = m0 + (tid >> 2);
        int rt = m >> 4, l15m = m & 15;
        int kc0 = (tid & 3) * 2;
        float s = 0.f;
#pragma unroll
        for (int kc = kc0; kc < kc0 + 2; ++kc)
#pragma unroll
          for (int ks = 0; ks < 2; ++ks)
#pragma unroll
            for (int q = 0; q < 4; ++q) {
              int off = (rt * 8 + kc) * 2048 + ks * 1024 + q * 256 + l15m * 16;
              v8h hv = aload16(h1base + off / 2);
              const float* w = pjw + kc * 64 + ks * 32 + q * 8;
#pragma unroll
              for (int e = 0; e < 8; ++e) s += (float)hv[e] * w[e];
            }
        part[tid] = s;
        __syncthreads();
        if (tid < 64) {
          float p4 = part[tid * 4] + part[tid * 4 + 1] + part[tid * 4 + 2] +
                     part[tid * 4 + 3] + ((float*)(smem + PROJB_OFF))[0];
          prevl[tid] = p4;
          if (hcTile == 0) out[(size_t)(m0 + tid) * TOUTN + (t - 1)] = p4;
        }
      }
      __syncthreads();
      if (t < TOUTN) {
        int sp = (u + 3) & 3, so = u & 3;
        const _Float16* h0prev =
            (const _Float16*)(hb + (size_t)(loc0 ? sp : 6 + sp) * HBYTES);
        stepDec0(tid, m0, hc0, flagsG, myflags, mySlot, u, h0prev,
                 (_Float16*)(hb + (size_t)so * HBYTES),
                 (_Float16*)(hb + (size_t)(6 + so) * HBYTES),
                 creg, flagLoc, loc0);
      }
    }
  } else {
    // ---------------- encoder layer 1 ----------------
    for (int s = 0; s < TINN; ++s) {
      int h0s = s & 3, h1p = 4 + ((s + 1) & 1), h1o = 4 + (s & 1);
      stepL1(tid, m0, hc0, flagsG, myflags, mySlot, s + 1, s + 2,
             (const _Float16*)(hb + (size_t)(loc0 ? h0s : 6 + h0s) * HBYTES),
             (const _Float16*)(hb + (size_t)(loc1 ? h1p : 6 + h1p) * HBYTES),
             (_Float16*)(hb + (size_t)h1o * HBYTES),
             (_Float16*)(hb + (size_t)(6 + h1o) * HBYTES),
             creg, flagLoc, loc0, loc1);
    }
    // ---------------- decoder layer 1 ----------------
    loadWeights(tid, hc0, d1wi, 512, 512, d1wh, 1024);
    if (tid < 64) {
      int n = (tid >> 4) * HHD + hc0 + (tid & 15);
      ((float*)(smem + BIAS_OFF))[tid] = d1bi[n] + d1bh[n];
    }
    for (int t = 0; t < TOUTN; ++t) {
      int u = TINN + t;
      int h0s = u & 3, h1p = 4 + ((u + 1) & 1), h1o = 4 + (u & 1);
      stepL1(tid, m0, hc0, flagsG, myflags, mySlot, u + 1, u + 2,
             (const _Float16*)(hb + (size_t)(loc0 ? h0s : 6 + h0s) * HBYTES),
             (const _Float16*)(hb + (size_t)(loc1 ? h1p : 6 + h1p) * HBYTES),
             (_Float16*)(hb + (size_t)h1o * HBYTES),
             (_Float16*)(hb + (size_t)(6 + h1o) * HBYTES),
             creg, flagLoc, loc0, loc1);
    }
  }
}

extern "C" void kernel_launch(void* const* d_in, const int* in_sizes, int n_in,
                              void* d_out, int out_size, void* d_ws, size_t ws_size,
                              hipStream_t stream) {
  const float* x = (const float*)d_in[0];
  const float* e0wi = (const float*)d_in[2];
  const float* e0wh = (const float*)d_in[3];
  const float* e0bi = (const float*)d_in[4];
  const float* e0bh = (const float*)d_in[5];
  const float* e1wi = (const float*)d_in[6];
  const float* e1wh = (const float*)d_in[7];
  const float* e1bi = (const float*)d_in[8];
  const float* e1bh = (const float*)d_in[9];
  const float* d0wi = (const float*)d_in[10];
  const float* d0wh = (const float*)d_in[11];
  const float* d0bi = (const float*)d_in[12];
  const float* d0bh = (const float*)d_in[13];
  const float* d1wi = (const float*)d_in[14];
  const float* d1wh = (const float*)d_in[15];
  const float* d1bi = (const float*)d_in[16];
  const float* d1bh = (const float*)d_in[17];
  const float* pw = (const float*)d_in[18];
  const float* pb = (const float*)d_in[19];

  (void)hipFuncSetAttribute((const void*)seq2seq_kernel,
                            hipFuncAttributeMaxDynamicSharedMemorySize, SMEM_TOTAL);
  (void)hipMemsetAsync(d_ws, 0, WS_FLAG_BYTES + WS_CENSUS_BYTES, stream);
  seq2seq_kernel<<<dim3(256), dim3(256), SMEM_TOTAL, stream>>>(
      x, e0wi, e0wh, e0bi, e0bh, e1wi, e1wh, e1bi, e1bh,
      d0wi, d0wh, d0bi, d0bh, d1wi, d1wh, d1bi, d1bh,
      pw, pb, (float*)d_out, (char*)d_ws);
}